// Round 1
// 680.779 us; speedup vs baseline: 1.1001x; 1.1001x over previous
//
#include <hip/hip_runtime.h>
#include <hip/hip_bf16.h>
#include <math.h>

// ---------------------------------------------------------------------------
// GPoolBlock, round 8: counted-vmcnt pipelined convs + cheap mish + vec epilogues.
//  - convs: triple-buffered A-tile (24KB LDS), stage 2 chunks ahead, B-frags
//    1 chunk ahead; raw s_barrier + asm s_waitcnt vmcnt(5) instead of
//    __syncthreads -> no vmcnt(0) drain per barrier (the measured stall:
//    MfmaUtil 19-27%, VALUBusy<28%, HBM<22% = nothing busy).
//    Invariant: per chunk each wave issues exactly 1 global_load_lds + 4
//    b-frag loads, so at chunk t's wait there are always exactly 5 VMEM ops
//    younger than stage(t) -> vmcnt(5) retires stage(t) precisely.
//  - mish via u=e^x: x*u*(u+2)/(u*(u+2)+2): 1 transcendental instead of 3.
//  - add_bn2_mish vectorized short8 (was scalar 2B/thread).
//  - lin fused into gpool kernel.
// Layouts: act channel-last zero-padded [b][441][C]; wfrag [cog][kc][lane][8].
// ---------------------------------------------------------------------------

#define BATCH   256
#define TRUNK_C 256
#define REG_C   192
#define GPOOL_C 64
#define HH      19
#define WW      19
#define HW      361
#define PP      441          // 21*21 padded pixels
#define EPS     1e-5f

typedef __hip_bfloat16 bf16;
typedef __attribute__((ext_vector_type(8))) short short8;
typedef __attribute__((ext_vector_type(4))) float floatx4;

__device__ __forceinline__ float b2f(bf16 v) { return __bfloat162float(v); }
__device__ __forceinline__ bf16  f2b(float v) { return __float2bfloat16(v); }

// mish(x) = x*tanh(softplus(x)); with u=e^x: tanh(log(1+u)) = u(u+2)/(u(u+2)+2)
__device__ __forceinline__ float mish_f(float v) {
    if (v > 20.0f) return v;           // tanh(softplus(20)) == 1 to fp32
    float u = __expf(v);
    float n = u * (u + 2.0f);
    return v * __fdividef(n, n + 2.0f);
}

__device__ __forceinline__ void gload_lds16(const void* gsrc, void* lds) {
    __builtin_amdgcn_global_load_lds(
        (const __attribute__((address_space(1))) void*)gsrc,
        (__attribute__((address_space(3))) void*)lds, 16, 0, 0);
}

// --------------------------- prep: fold BN params ---------------------------
// bnbuf: [0:256] bn1_s [256:512] bn1_b [512:576] bn1b_s [576:640] bn1b_b
//        [640:832] bn2_s [832:1024] bn2_b
__global__ void prep_bn_kernel(const float* g1, const float* b1, const float* m1, const float* v1,
                               const float* g1b, const float* b1b, const float* m1b, const float* v1b,
                               const float* g2, const float* b2, const float* m2, const float* v2,
                               float* bnbuf) {
    int t = threadIdx.x;
    if (t < 256) {
        float s = g1[t] / sqrtf(v1[t] + EPS);
        bnbuf[t] = s;
        bnbuf[256 + t] = b1[t] - m1[t] * s;
    } else if (t < 320) {
        int c = t - 256;
        float s = g1b[c] / sqrtf(v1b[c] + EPS);
        bnbuf[512 + c] = s;
        bnbuf[576 + c] = b1b[c] - m1b[c] * s;
    } else if (t < 512) {
        int c = t - 320;
        float s = g2[c] / sqrtf(v2[c] + EPS);
        bnbuf[640 + c] = s;
        bnbuf[832 + c] = b2[c] - m2[c] * s;
    }
}

// ------------- prep: weights -> MFMA-fragment layout (bf16) -----------------
// w1c_p[((cog*72 + kc)*64 + lane)*8 + j]: co = cog*16 + (lane&15),
//   k = kc*32 + (lane>>4)*8 + j, r = k>>8, ci = k&255;
//   co<192 -> w1a, else w1b (combined 256-co matrix).
// w2_p analogous with K=1728 (kc 54), CIN=192.
__global__ void prep_w_kernel(const float* __restrict__ w1a, const float* __restrict__ w1b,
                              const float* __restrict__ w2,
                              bf16* __restrict__ w1c_p, bf16* __restrict__ w2_p) {
    const int T1 = 16 * 72 * 64 * 8;     // 589824
    const int T2 = 16 * 54 * 64 * 8;     // 442368
    for (int i = blockIdx.x * blockDim.x + threadIdx.x; i < T1 + T2;
         i += gridDim.x * blockDim.x) {
        if (i < T1) {
            int j = i & 7, lane = (i >> 3) & 63;
            int kc = (i >> 9) % 72, cog = (i >> 9) / 72;
            int co = cog * 16 + (lane & 15);
            int k = kc * 32 + ((lane >> 4) << 3) + j;
            int r = k >> 8, ci = k & 255;
            float v = (co < 192) ? w1a[co * 2304 + ci * 9 + r]
                                 : w1b[(co - 192) * 2304 + ci * 9 + r];
            w1c_p[i] = f2b(v);
        } else {
            int i2 = i - T1;
            int j = i2 & 7, lane = (i2 >> 3) & 63;
            int kc = (i2 >> 9) % 54, cog = (i2 >> 9) / 54;
            int co = cog * 16 + (lane & 15);
            int k = kc * 32 + ((lane >> 4) << 3) + j;
            int r = k / 192, ci = k % 192;
            w2_p[i2] = f2b(w2[co * 1728 + ci * 9 + r]);
        }
    }
}

// ---------------- zero the padded borders of act_pad and reg_pad ------------
__global__ void zero_border_kernel(bf16* __restrict__ act_pad, bf16* __restrict__ reg_pad) {
    int b = blockIdx.x;
    int t = threadIdx.x;     // 256
    for (int pp = 0; pp < PP; ++pp) {
        int r = pp / 21, c = pp % 21;
        bool border = (r == 0) | (r == 20) | (c == 0) | (c == 20);
        if (!border) continue;
        act_pad[((size_t)b * PP + pp) * TRUNK_C + t] = f2b(0.0f);
        if (t < REG_C) reg_pad[((size_t)b * PP + pp) * REG_C + t] = f2b(0.0f);
    }
}

// ------- bn1+mish + LDS transpose: x [b][256][361] fp32 -> act_pad CL bf16 --
__global__ __launch_bounds__(256)
void bn1_mish_t_kernel(const float* __restrict__ x, const float* __restrict__ bnbuf,
                       bf16* __restrict__ act_pad) {
    __shared__ float lds[256][32];    // XOR-swizzled columns
    int pc = blockIdx.x;              // pixel chunk of 32 (12 chunks)
    int b  = blockIdx.y;
    int t  = threadIdx.x;
    int p0 = pc * 32;
    int px = t & 31;
#pragma unroll
    for (int it = 0; it < 32; ++it) {          // 32 passes x 8 channels = 256
        int ci = it * 8 + (t >> 5);
        int p  = p0 + px;
        float v = 0.0f;
        if (p < HW) v = x[((size_t)b * TRUNK_C + ci) * HW + p];
        v = v * bnbuf[ci] + bnbuf[256 + ci];
        lds[ci][px ^ (ci >> 3)] = mish_f(v);
    }
    __syncthreads();
#pragma unroll
    for (int it = 0; it < 4; ++it) {
        int pl = it * 8 + (t >> 5);
        int p  = p0 + pl;
        if (p >= HW) continue;
        int ch = t & 31;                       // channel block: ch*8 .. ch*8+7
        short8 vv;
#pragma unroll
        for (int j = 0; j < 8; ++j) {
            bf16 h = f2b(lds[ch * 8 + j][pl ^ ch]);
            short s;
            __builtin_memcpy(&s, &h, 2);
            vv[j] = s;
        }
        int pp = (p / WW + 1) * 21 + (p % WW + 1);
        *(short8*)(act_pad + ((size_t)b * PP + pp) * TRUNK_C + ch * 8) = vv;
    }
}

// ---------------------- conv1 fused (act x W -> 256 co) ---------------------
// Block: 512 thr (8 waves, mi 0..1 x ni 0..3). Tile M=128 px, N=256 co, BK=32.
// A-tile triple-buffered (stage 2 chunks ahead), B-frags prefetched 1 chunk
// ahead. Raw s_barrier + counted vmcnt(5): per chunk each wave issues exactly
// {1 stage, 4 bfrag loads}, so 5 VMEM ops are always younger than stage(t).
__global__ __launch_bounds__(512)
void conv1_kernel(const bf16* __restrict__ act,     // [b][441][256]
                  const bf16* __restrict__ wfrag,   // [16][72][64][8]
                  bf16* __restrict__ reg_out,       // [b][441][192]
                  bf16* __restrict__ gp_out,        // [b][361][64]
                  const float* __restrict__ ep_scale, const float* __restrict__ ep_bias) {
    const int CIN = 256, NKC = 72;
    __shared__ __align__(16) bf16 atile[3][128 * 32];
    const int b   = blockIdx.x;
    const int mt  = blockIdx.y;
    const int t   = threadIdx.x;
    const int w   = t >> 6, lane = t & 63;
    const int mi  = w >> 2, ni = w & 3;
    const int l15 = lane & 15, quad = lane >> 4;

    // staging source: thread t loads 16B of pixel row (t>>2), sub-chunk swizzled
    int spxl = t >> 2;                       // 0..127 LDS row
    int sq   = t & 3;
    int ss   = sq ^ ((spxl >> 1) & 3);       // swizzled ci sub-chunk
    int sp   = mt * 128 + spxl; if (sp > 360) sp = 360;
    const bf16* sbase = act + ((size_t)b * PP + (sp / WW) * 21 + (sp % WW)) * CIN + (ss << 3);

    // B-frag bases (fragmented weights): cog = ni*4+ns
    const bf16* wb[4];
#pragma unroll
    for (int ns = 0; ns < 4; ++ns)
        wb[ns] = wfrag + ((size_t)(ni * 4 + ns) * NKC * 64 + lane) * 8;

    // A-frag LDS element offsets (within one buffer)
    int aoff[4];
#pragma unroll
    for (int ms = 0; ms < 4; ++ms) {
        int row = mi * 64 + ms * 16 + l15;
        aoff[ms] = row * 32 + ((quad ^ ((row >> 1) & 3)) << 3);
    }

    auto stage = [&](int buf, int kc) {
        int r = kc >> 3, c = kc & 7;
        int off = ((r / 3) * 21 + (r % 3)) * CIN + (c << 5);
        gload_lds16(sbase + off, &atile[buf][w << 9]);
    };

    floatx4 acc[4][4];
#pragma unroll
    for (int i = 0; i < 4; ++i)
#pragma unroll
        for (int j = 0; j < 4; ++j) acc[i][j] = (floatx4){0.f, 0.f, 0.f, 0.f};

    short8 afr[4], bfrA[4], bfrB[4];
    // prologue: chunks 0,1 staged; bfr(0) loaded. Outstanding: [st0, st1, b0x4].
    stage(0, 0);
    stage(1, 1);
#pragma unroll
    for (int ns = 0; ns < 4; ++ns) bfrA[ns] = *(const short8*)(wb[ns]);

    for (int kc = 0; kc < NKC; kc += 2) {
        // ---- chunk kc: buffer kc%3, frags bfrA ----
        asm volatile("s_waitcnt vmcnt(5)" ::: "memory");   // stage(kc) retired
        __builtin_amdgcn_sched_barrier(0);
        __builtin_amdgcn_s_barrier();                       // all waves' stage(kc) done;
        __builtin_amdgcn_sched_barrier(0);                  // all reads of chunk kc-1 done
        {
            int s1 = kc + 2; if (s1 > NKC - 1) s1 = NKC - 1;  // clamp keeps counts uniform
            stage((kc + 2) % 3, s1);
        }
#pragma unroll
        for (int ns = 0; ns < 4; ++ns)
            bfrB[ns] = *(const short8*)(wb[ns] + (size_t)(kc + 1) * 512);
        {
            const bf16* at = atile[kc % 3];
#pragma unroll
            for (int ms = 0; ms < 4; ++ms)
                afr[ms] = *(const short8*)(at + aoff[ms]);
        }
#pragma unroll
        for (int ms = 0; ms < 4; ++ms)
#pragma unroll
            for (int ns = 0; ns < 4; ++ns)
                acc[ms][ns] = __builtin_amdgcn_mfma_f32_16x16x32_bf16(
                    afr[ms], bfrA[ns], acc[ms][ns], 0, 0, 0);

        // ---- chunk kc+1: buffer (kc+1)%3, frags bfrB ----
        asm volatile("s_waitcnt vmcnt(5)" ::: "memory");   // stage(kc+1) retired
        __builtin_amdgcn_sched_barrier(0);
        __builtin_amdgcn_s_barrier();
        __builtin_amdgcn_sched_barrier(0);
        {
            int s2 = kc + 3; if (s2 > NKC - 1) s2 = NKC - 1;
            stage((kc + 3) % 3, s2);
        }
        {
            int nb = kc + 2; if (nb > NKC - 1) nb = NKC - 1;
#pragma unroll
            for (int ns = 0; ns < 4; ++ns)
                bfrA[ns] = *(const short8*)(wb[ns] + (size_t)nb * 512);
        }
        {
            const bf16* at = atile[(kc + 1) % 3];
#pragma unroll
            for (int ms = 0; ms < 4; ++ms)
                afr[ms] = *(const short8*)(at + aoff[ms]);
        }
#pragma unroll
        for (int ms = 0; ms < 4; ++ms)
#pragma unroll
            for (int ns = 0; ns < 4; ++ns)
                acc[ms][ns] = __builtin_amdgcn_mfma_f32_16x16x32_bf16(
                    afr[ms], bfrB[ns], acc[ms][ns], 0, 0, 0);
    }

    // epilogue: D rows = px (quad*4+rg), cols = co (l15)
    float scl[4], bia[4];
#pragma unroll
    for (int ns = 0; ns < 4; ++ns) {
        int co = (ni * 4 + ns) * 16 + l15;
        if (co >= 192) { scl[ns] = ep_scale[co - 192]; bia[ns] = ep_bias[co - 192]; }
    }
#pragma unroll
    for (int ms = 0; ms < 4; ++ms) {
#pragma unroll
        for (int rg = 0; rg < 4; ++rg) {
            int p = mt * 128 + mi * 64 + ms * 16 + quad * 4 + rg;
            if (p > 360) continue;
            size_t ppad = (size_t)b * PP + (p / WW + 1) * 21 + (p % WW + 1);
#pragma unroll
            for (int ns = 0; ns < 4; ++ns) {
                int co = (ni * 4 + ns) * 16 + l15;
                float v = acc[ms][ns][rg];
                if (co < 192) {
                    reg_out[ppad * REG_C + co] = f2b(v);
                } else {
                    v = mish_f(v * scl[ns] + bia[ns]);
                    gp_out[((size_t)b * HW + p) * GPOOL_C + (co - 192)] = f2b(v);
                }
            }
        }
    }
}

// ------------------- conv2 (W x act -> channel-first fp32) ------------------
// Same pipeline as conv1. A = fragmented weights (rows=co), B = act frags.
__global__ __launch_bounds__(512)
void conv2_kernel(const bf16* __restrict__ act,     // reg_pad [b][441][192]
                  const bf16* __restrict__ wfrag,   // [16][54][64][8]
                  const float* __restrict__ resid,
                  float* __restrict__ out) {
    const int CIN = 192, NKC = 54;
    __shared__ __align__(16) bf16 atile[3][128 * 32];
    const int b   = blockIdx.x;
    const int mt  = blockIdx.y;
    const int t   = threadIdx.x;
    const int w   = t >> 6, lane = t & 63;
    const int pw  = w >> 2, cw = w & 3;
    const int l15 = lane & 15, quad = lane >> 4;

    int spxl = t >> 2;
    int sq   = t & 3;
    int ss   = sq ^ ((spxl >> 1) & 3);
    int sp   = mt * 128 + spxl; if (sp > 360) sp = 360;
    const bf16* sbase = act + ((size_t)b * PP + (sp / WW) * 21 + (sp % WW)) * CIN + (ss << 3);

    const bf16* wb[4];
#pragma unroll
    for (int ms = 0; ms < 4; ++ms)
        wb[ms] = wfrag + ((size_t)(cw * 4 + ms) * NKC * 64 + lane) * 8;

    int aoff[4];
#pragma unroll
    for (int ns = 0; ns < 4; ++ns) {
        int row = pw * 64 + ns * 16 + l15;
        aoff[ns] = row * 32 + ((quad ^ ((row >> 1) & 3)) << 3);
    }

    auto stage = [&](int buf, int kc) {
        int r = kc / 6, c = kc % 6;
        int off = ((r / 3) * 21 + (r % 3)) * CIN + (c << 5);
        gload_lds16(sbase + off, &atile[buf][w << 9]);
    };

    floatx4 acc[4][4];
#pragma unroll
    for (int i = 0; i < 4; ++i)
#pragma unroll
        for (int j = 0; j < 4; ++j) acc[i][j] = (floatx4){0.f, 0.f, 0.f, 0.f};

    short8 bfa[4], wfrA[4], wfrB[4];
    stage(0, 0);
    stage(1, 1);
#pragma unroll
    for (int ms = 0; ms < 4; ++ms) wfrA[ms] = *(const short8*)(wb[ms]);

    for (int kc = 0; kc < NKC; kc += 2) {
        // ---- chunk kc: buffer kc%3, frags wfrA ----
        asm volatile("s_waitcnt vmcnt(5)" ::: "memory");
        __builtin_amdgcn_sched_barrier(0);
        __builtin_amdgcn_s_barrier();
        __builtin_amdgcn_sched_barrier(0);
        {
            int s1 = kc + 2; if (s1 > NKC - 1) s1 = NKC - 1;
            stage((kc + 2) % 3, s1);
        }
#pragma unroll
        for (int ms = 0; ms < 4; ++ms)
            wfrB[ms] = *(const short8*)(wb[ms] + (size_t)(kc + 1) * 512);
        {
            const bf16* at = atile[kc % 3];
#pragma unroll
            for (int ns = 0; ns < 4; ++ns)
                bfa[ns] = *(const short8*)(at + aoff[ns]);
        }
#pragma unroll
        for (int ms = 0; ms < 4; ++ms)
#pragma unroll
            for (int ns = 0; ns < 4; ++ns)
                acc[ms][ns] = __builtin_amdgcn_mfma_f32_16x16x32_bf16(
                    wfrA[ms], bfa[ns], acc[ms][ns], 0, 0, 0);

        // ---- chunk kc+1: buffer (kc+1)%3, frags wfrB ----
        asm volatile("s_waitcnt vmcnt(5)" ::: "memory");
        __builtin_amdgcn_sched_barrier(0);
        __builtin_amdgcn_s_barrier();
        __builtin_amdgcn_sched_barrier(0);
        {
            int s2 = kc + 3; if (s2 > NKC - 1) s2 = NKC - 1;
            stage((kc + 3) % 3, s2);
        }
        {
            int nb = kc + 2; if (nb > NKC - 1) nb = NKC - 1;
#pragma unroll
            for (int ms = 0; ms < 4; ++ms)
                wfrA[ms] = *(const short8*)(wb[ms] + (size_t)nb * 512);
        }
        {
            const bf16* at = atile[(kc + 1) % 3];
#pragma unroll
            for (int ns = 0; ns < 4; ++ns)
                bfa[ns] = *(const short8*)(at + aoff[ns]);
        }
#pragma unroll
        for (int ms = 0; ms < 4; ++ms)
#pragma unroll
            for (int ns = 0; ns < 4; ++ns)
                acc[ms][ns] = __builtin_amdgcn_mfma_f32_16x16x32_bf16(
                    wfrB[ms], bfa[ns], acc[ms][ns], 0, 0, 0);
    }

    // epilogue: D rows = co (quad*4+rg), cols = px (l15)
#pragma unroll
    for (int ns = 0; ns < 4; ++ns) {
        int p = mt * 128 + pw * 64 + ns * 16 + l15;
        if (p > 360) continue;
#pragma unroll
        for (int ms = 0; ms < 4; ++ms) {
#pragma unroll
            for (int rg = 0; rg < 4; ++rg) {
                int co = (cw * 4 + ms) * 16 + quad * 4 + rg;
                size_t idx = ((size_t)b * TRUNK_C + co) * HW + p;
                out[idx] = acc[ms][ns][rg] + resid[idx];
            }
        }
    }
}

// --------------------- kata gpool + fused 192x192 linear --------------------
__global__ void gpool_lin_kernel(const bf16* __restrict__ gp, const float* __restrict__ w_lin,
                                 float* __restrict__ gpout) {
    __shared__ float ls[4][64], lm[4][64];
    __shared__ float pooled_s[192];
    int b = blockIdx.x;
    int t = threadIdx.x;          // 256
    int c = t & 63, sub = t >> 6;
    float s = 0.0f, mx = -1e30f;
    for (int p = sub; p < HW; p += 4) {
        float v = b2f(gp[((size_t)b * HW + p) * GPOOL_C + c]);
        s += v;
        mx = fmaxf(mx, v);
    }
    ls[sub][c] = s; lm[sub][c] = mx;
    __syncthreads();
    if (t < 64) {
        float ss = ls[0][t] + ls[1][t] + ls[2][t] + ls[3][t];
        float mm = fmaxf(fmaxf(lm[0][t], lm[1][t]), fmaxf(lm[2][t], lm[3][t]));
        float mean = ss * (1.0f / 361.0f);
        pooled_s[t] = mean;
        pooled_s[64 + t] = mean * 0.5f;     // (sqrt(361)-14)/10
        pooled_s[128 + t] = mm;
    }
    __syncthreads();
    if (t < 192) {
        const float4* wr4 = (const float4*)(w_lin + t * 192);
        float acc = 0.0f;
#pragma unroll 8
        for (int j = 0; j < 48; ++j) {
            float4 wv = wr4[j];
            acc = fmaf(pooled_s[j * 4 + 0], wv.x, acc);
            acc = fmaf(pooled_s[j * 4 + 1], wv.y, acc);
            acc = fmaf(pooled_s[j * 4 + 2], wv.z, acc);
            acc = fmaf(pooled_s[j * 4 + 3], wv.w, acc);
        }
        gpout[b * 192 + t] = acc;
    }
}

// ------------- add gpool bias + bn2 + mish, in-place on reg_pad -------------
// short8-vectorized: one thread per 8 channels (24 groups/pixel).
__global__ __launch_bounds__(256)
void add_bn2_mish_kernel(bf16* __restrict__ reg_pad, const float* __restrict__ gpout,
                         const float* __restrict__ bnbuf) {
    const int total = BATCH * HW * 24;
    int i = blockIdx.x * blockDim.x + threadIdx.x;
    if (i >= total) return;
    int g  = i % 24;
    int bp = i / 24;
    int p  = bp % HW;
    int b  = bp / HW;
    int pp = (p / WW + 1) * 21 + (p % WW + 1);
    size_t idx = ((size_t)b * PP + pp) * REG_C + g * 8;
    short8 v = *(const short8*)(reg_pad + idx);
    const float* gpo = gpout + b * 192 + g * 8;
    const float* sc  = bnbuf + 640 + g * 8;
    const float* bi  = bnbuf + 832 + g * 8;
    short8 o;
#pragma unroll
    for (int j = 0; j < 8; ++j) {
        short sj = v[j];
        bf16 h;
        __builtin_memcpy(&h, &sj, 2);
        float f = b2f(h) + gpo[j];
        f = f * sc[j] + bi[j];
        h = f2b(mish_f(f));
        __builtin_memcpy(&sj, &h, 2);
        o[j] = sj;
    }
    *(short8*)(reg_pad + idx) = o;
}

// ---------------------------------------------------------------------------
extern "C" void kernel_launch(void* const* d_in, const int* in_sizes, int n_in,
                              void* d_out, int out_size, void* d_ws, size_t ws_size,
                              hipStream_t stream) {
    const float* x     = (const float*)d_in[0];
    const float* bn1_g = (const float*)d_in[1];
    const float* bn1_b = (const float*)d_in[2];
    const float* bn1_m = (const float*)d_in[3];
    const float* bn1_v = (const float*)d_in[4];
    const float* w1a   = (const float*)d_in[5];
    const float* w1b   = (const float*)d_in[6];
    const float* bn1b_g = (const float*)d_in[7];
    const float* bn1b_b = (const float*)d_in[8];
    const float* bn1b_m = (const float*)d_in[9];
    const float* bn1b_v = (const float*)d_in[10];
    const float* w_lin  = (const float*)d_in[11];
    const float* bn2_g  = (const float*)d_in[12];
    const float* bn2_b  = (const float*)d_in[13];
    const float* bn2_m  = (const float*)d_in[14];
    const float* bn2_v  = (const float*)d_in[15];
    const float* w2     = (const float*)d_in[16];
    float* out = (float*)d_out;

    char* ws = (char*)d_ws;
    size_t off = 0;
    auto alloc = [&](size_t bytes) {
        void* p = ws + off;
        off += (bytes + 255) & ~(size_t)255;
        return p;
    };
    bf16*  act_pad = (bf16*)alloc((size_t)BATCH * PP * TRUNK_C * sizeof(bf16));
    bf16*  reg_pad = (bf16*)alloc((size_t)BATCH * PP * REG_C * sizeof(bf16));
    bf16*  gp      = (bf16*)alloc((size_t)BATCH * HW * GPOOL_C * sizeof(bf16));
    bf16*  w1c_p   = (bf16*)alloc((size_t)16 * 72 * 64 * 8 * sizeof(bf16));
    bf16*  w2_p    = (bf16*)alloc((size_t)16 * 54 * 64 * 8 * sizeof(bf16));
    float* gpout   = (float*)alloc((size_t)BATCH * 192 * sizeof(float));
    float* bnbuf   = (float*)alloc(1024 * sizeof(float));
    (void)ws_size;

    // 1. prep
    hipLaunchKernelGGL(prep_bn_kernel, dim3(1), dim3(512), 0, stream,
                       bn1_g, bn1_b, bn1_m, bn1_v,
                       bn1b_g, bn1b_b, bn1b_m, bn1b_v,
                       bn2_g, bn2_b, bn2_m, bn2_v, bnbuf);
    hipLaunchKernelGGL(prep_w_kernel, dim3(1024), dim3(256), 0, stream,
                       w1a, w1b, w2, w1c_p, w2_p);
    hipLaunchKernelGGL(zero_border_kernel, dim3(BATCH), dim3(256), 0, stream,
                       act_pad, reg_pad);

    // 2. act_pad = mish(bn1(x)), LDS-tiled transpose to channel-last padded
    hipLaunchKernelGGL(bn1_mish_t_kernel, dim3(12, BATCH), dim3(256), 0, stream,
                       x, bnbuf, act_pad);

    // 3. fused conv1: reg_pad raw interior + gp = mish(bn1b(conv))
    hipLaunchKernelGGL(conv1_kernel, dim3(BATCH, 3), dim3(512), 0, stream,
                       act_pad, w1c_p, reg_pad, gp, bnbuf + 512, bnbuf + 576);

    // 4. pooled = kata_gpool(gp); gpout = pooled @ w_lin^T (fused)
    hipLaunchKernelGGL(gpool_lin_kernel, dim3(BATCH), dim3(256), 0, stream,
                       gp, w_lin, gpout);

    // 5. reg_pad = mish(bn2(reg_pad + gpout)) in-place (interior only)
    {
        int total = BATCH * HW * 24;
        hipLaunchKernelGGL(add_bn2_mish_kernel, dim3((total + 255) / 256), dim3(256), 0, stream,
                           reg_pad, gpout, bnbuf);
    }

    // 6. out = conv(reg_pad, w2) + x, channel-first fp32
    hipLaunchKernelGGL(conv2_kernel, dim3(BATCH, 3), dim3(512), 0, stream,
                       reg_pad, w2_p, x, out);
}

// Round 2
// 669.174 us; speedup vs baseline: 1.1192x; 1.0173x over previous
//
#include <hip/hip_runtime.h>
#include <hip/hip_bf16.h>
#include <math.h>

// ---------------------------------------------------------------------------
// GPoolBlock, round 9: 4-wave conv blocks (3-4 co-resident/CU) + depth-3 stage.
//  - convs: tile 128px x 128co, 4 waves/block, grid (B,3,2). Per-wave work
//    unchanged; occupancy granularity 4 waves -> 12+ waves/CU vs round-8's
//    8 (measured occ 34.5%, MfmaUtil 23% = ~1 8-wave block resident).
//  - A-tile staged 3 chunks ahead (4 buffers, 32KB LDS). Counted waits:
//    per chunk each wave issues {4 bfrag, 2 stage} VMEM ops in that order
//    (compiler memory fences pin it) -> vmcnt(12) steady / vmcnt(8) chunk 0.
//  - prep_bn + prep_w + zero_border fused into one launch; border zeroing
//    short8-vectorized (was scalar 2B stores over 441 iterations).
// Layouts: act channel-last zero-padded [b][441][C]; wfrag [cog][kc][lane][8].
// ---------------------------------------------------------------------------

#define BATCH   256
#define TRUNK_C 256
#define REG_C   192
#define GPOOL_C 64
#define HH      19
#define WW      19
#define HW      361
#define PP      441          // 21*21 padded pixels
#define EPS     1e-5f

typedef __hip_bfloat16 bf16;
typedef __attribute__((ext_vector_type(8))) short short8;
typedef __attribute__((ext_vector_type(4))) float floatx4;

__device__ __forceinline__ float b2f(bf16 v) { return __bfloat162float(v); }
__device__ __forceinline__ bf16  f2b(float v) { return __float2bfloat16(v); }

// mish(x) = x*tanh(softplus(x)); with u=e^x: tanh(log(1+u)) = u(u+2)/(u(u+2)+2)
__device__ __forceinline__ float mish_f(float v) {
    if (v > 20.0f) return v;           // tanh(softplus(20)) == 1 to fp32
    float u = __expf(v);
    float n = u * (u + 2.0f);
    return v * __fdividef(n, n + 2.0f);
}

__device__ __forceinline__ void gload_lds16(const void* gsrc, void* lds) {
    __builtin_amdgcn_global_load_lds(
        (const __attribute__((address_space(1))) void*)gsrc,
        (__attribute__((address_space(3))) void*)lds, 16, 0, 0);
}

// ---------------- fused prep: BN fold + weight frags + border zero ----------
// bnbuf: [0:256] bn1_s [256:512] bn1_b [512:576] bn1b_s [576:640] bn1b_b
//        [640:832] bn2_s [832:1024] bn2_b
// w1c_p[((cog*72 + kc)*64 + lane)*8 + j]: co = cog*16 + (lane&15),
//   k = kc*32 + (lane>>4)*8 + j, r = k>>8, ci = k&255; co<192 -> w1a else w1b.
// w2_p analogous with K=1728 (kc 54), CIN=192.
__global__ void prep_kernel(
    const float* g1, const float* b1, const float* m1, const float* v1,
    const float* g1b, const float* b1b, const float* m1b, const float* v1b,
    const float* g2, const float* b2, const float* m2, const float* v2,
    const float* __restrict__ w1a, const float* __restrict__ w1b,
    const float* __restrict__ w2,
    bf16* __restrict__ w1c_p, bf16* __restrict__ w2_p,
    bf16* __restrict__ act_pad, bf16* __restrict__ reg_pad,
    float* bnbuf)
{
    const int T1  = 16 * 72 * 64 * 8;     // 589824
    const int T2  = 16 * 54 * 64 * 8;     // 442368
    const int TW  = T1 + T2;              // 1032192
    const int TBa = BATCH * 80 * 32;      // act border short8 groups 655360
    const int TBr = BATCH * 80 * 24;      // reg border short8 groups 491520
    int i = blockIdx.x * blockDim.x + threadIdx.x;
    if (i < TW) {
        if (i < T1) {
            int j = i & 7, lane = (i >> 3) & 63;
            int kc = (i >> 9) % 72, cog = (i >> 9) / 72;
            int co = cog * 16 + (lane & 15);
            int k = kc * 32 + ((lane >> 4) << 3) + j;
            int r = k >> 8, ci = k & 255;
            float v = (co < 192) ? w1a[co * 2304 + ci * 9 + r]
                                 : w1b[(co - 192) * 2304 + ci * 9 + r];
            w1c_p[i] = f2b(v);
        } else {
            int i2 = i - T1;
            int j = i2 & 7, lane = (i2 >> 3) & 63;
            int kc = (i2 >> 9) % 54, cog = (i2 >> 9) / 54;
            int co = cog * 16 + (lane & 15);
            int k = kc * 32 + ((lane >> 4) << 3) + j;
            int r = k / 192, ci = k % 192;
            w2_p[i2] = f2b(w2[co * 1728 + ci * 9 + r]);
        }
    } else if (i < TW + TBa + TBr) {
        int j = i - TW;
        bool isact = j < TBa;
        if (!isact) j -= TBa;
        int nb = isact ? 32 : 24;
        int b = j / (80 * nb);
        int rem = j - b * (80 * nb);
        int e = rem / nb, g = rem - (rem / nb) * nb;
        int pp;
        if (e < 21) pp = e;                        // row 0
        else if (e < 42) pp = 420 + (e - 21);      // row 20
        else if (e < 61) pp = (e - 41) * 21;       // col 0, rows 1..19
        else pp = (e - 60) * 21 + 20;              // col 20, rows 1..19
        short8 z = {0, 0, 0, 0, 0, 0, 0, 0};
        if (isact) *(short8*)(act_pad + ((size_t)b * PP + pp) * TRUNK_C + g * 8) = z;
        else       *(short8*)(reg_pad + ((size_t)b * PP + pp) * REG_C + g * 8) = z;
    } else {
        int t = i - (TW + TBa + TBr);
        if (t < 256) {
            float s = g1[t] / sqrtf(v1[t] + EPS);
            bnbuf[t] = s;
            bnbuf[256 + t] = b1[t] - m1[t] * s;
        } else if (t < 320) {
            int c = t - 256;
            float s = g1b[c] / sqrtf(v1b[c] + EPS);
            bnbuf[512 + c] = s;
            bnbuf[576 + c] = b1b[c] - m1b[c] * s;
        } else if (t < 512) {
            int c = t - 320;
            float s = g2[c] / sqrtf(v2[c] + EPS);
            bnbuf[640 + c] = s;
            bnbuf[832 + c] = b2[c] - m2[c] * s;
        }
    }
}

// ------- bn1+mish + LDS transpose: x [b][256][361] fp32 -> act_pad CL bf16 --
__global__ __launch_bounds__(256)
void bn1_mish_t_kernel(const float* __restrict__ x, const float* __restrict__ bnbuf,
                       bf16* __restrict__ act_pad) {
    __shared__ float lds[256][32];    // XOR-swizzled columns
    int pc = blockIdx.x;              // pixel chunk of 32 (12 chunks)
    int b  = blockIdx.y;
    int t  = threadIdx.x;
    int p0 = pc * 32;
    int px = t & 31;
#pragma unroll
    for (int it = 0; it < 32; ++it) {          // 32 passes x 8 channels = 256
        int ci = it * 8 + (t >> 5);
        int p  = p0 + px;
        float v = 0.0f;
        if (p < HW) v = x[((size_t)b * TRUNK_C + ci) * HW + p];
        v = v * bnbuf[ci] + bnbuf[256 + ci];
        lds[ci][px ^ (ci >> 3)] = mish_f(v);
    }
    __syncthreads();
#pragma unroll
    for (int it = 0; it < 4; ++it) {
        int pl = it * 8 + (t >> 5);
        int p  = p0 + pl;
        if (p >= HW) continue;
        int ch = t & 31;                       // channel block: ch*8 .. ch*8+7
        short8 vv;
#pragma unroll
        for (int j = 0; j < 8; ++j) {
            bf16 h = f2b(lds[ch * 8 + j][pl ^ ch]);
            short s;
            __builtin_memcpy(&s, &h, 2);
            vv[j] = s;
        }
        int pp = (p / WW + 1) * 21 + (p % WW + 1);
        *(short8*)(act_pad + ((size_t)b * PP + pp) * TRUNK_C + ch * 8) = vv;
    }
}

// ---------------------- conv1 fused (act x W -> 256 co) ---------------------
// Block: 256 thr (4 waves: mi 0..1 x ni 0..1). Tile M=128 px, N=128 co
// (blockIdx.z picks co half). BK=32, A-tile 4-deep (staged 3 ahead, 32KB).
// Per chunk each wave: 4 bfrag loads then 2 stage ops; vmcnt(12)/(8@kc0).
// co<192 -> reg_pad raw (padded CL); co>=192 -> gp (bn1b+mish, CL).
__global__ __launch_bounds__(256, 3)
void conv1_kernel(const bf16* __restrict__ act,     // [b][441][256]
                  const bf16* __restrict__ wfrag,   // [16][72][64][8]
                  bf16* __restrict__ reg_out,       // [b][441][192]
                  bf16* __restrict__ gp_out,        // [b][361][64]
                  const float* __restrict__ ep_scale, const float* __restrict__ ep_bias) {
    const int CIN = 256, NKC = 72;
    __shared__ __align__(16) bf16 atile[4][128 * 32];
    const int b   = blockIdx.x;
    const int mt  = blockIdx.y;
    const int nh  = blockIdx.z;       // co half (0: co 0..127, 1: 128..255)
    const int t   = threadIdx.x;
    const int w   = t >> 6, lane = t & 63;
    const int mi  = w >> 1, ni = w & 1;
    const int l15 = lane & 15, quad = lane >> 4;

    // staging: thread t covers LDS rows (t>>2) and (t>>2)+64, 16B sub-chunk
    int row0 = t >> 2;
    int sq   = t & 3;
    int ss   = sq ^ ((row0 >> 1) & 3);       // swizzled ci sub-chunk (same for both rows)
    int sp0  = mt * 128 + row0;      if (sp0 > 360) sp0 = 360;
    int sp1  = mt * 128 + row0 + 64; if (sp1 > 360) sp1 = 360;
    const bf16* sb0 = act + ((size_t)b * PP + (sp0 / WW) * 21 + (sp0 % WW)) * CIN + (ss << 3);
    const bf16* sb1 = act + ((size_t)b * PP + (sp1 / WW) * 21 + (sp1 % WW)) * CIN + (ss << 3);

    // B-frag bases: cog = nh*8 + ni*4 + ns
    const bf16* wb[4];
#pragma unroll
    for (int ns = 0; ns < 4; ++ns)
        wb[ns] = wfrag + ((size_t)(nh * 8 + ni * 4 + ns) * NKC * 64 + lane) * 8;

    // A-frag LDS element offsets (within one buffer)
    int aoff[4];
#pragma unroll
    for (int ms = 0; ms < 4; ++ms) {
        int row = mi * 64 + ms * 16 + l15;
        aoff[ms] = row * 32 + ((quad ^ ((row >> 1) & 3)) << 3);
    }

    auto stage = [&](int buf, int kc) {
        int r = kc >> 3, c = kc & 7;
        int off = ((r / 3) * 21 + (r % 3)) * CIN + (c << 5);
        bf16* dst = &atile[buf][w << 9];         // wave rows w*16..w*16+15
        gload_lds16(sb0 + off, dst);
        gload_lds16(sb1 + off, dst + 2048);      // rows 64+w*16..
    };

    floatx4 acc[4][4];
#pragma unroll
    for (int i = 0; i < 4; ++i)
#pragma unroll
        for (int j = 0; j < 4; ++j) acc[i][j] = (floatx4){0.f, 0.f, 0.f, 0.f};

    short8 afr[4], bfrA[4], bfrB[4];
    // prologue issue order (fenced): S0, S1, B0, S2
    stage(0, 0);
    stage(1, 1);
    asm volatile("" ::: "memory");
#pragma unroll
    for (int ns = 0; ns < 4; ++ns) bfrA[ns] = *(const short8*)(wb[ns]);
    asm volatile("" ::: "memory");
    stage(2, 2);

    for (int kc = 0; kc < NKC; kc += 2) {
        // ---- chunk kc: buffer kc&3, frags bfrA ----
        if (kc == 0) asm volatile("s_waitcnt vmcnt(8)" ::: "memory");
        else         asm volatile("s_waitcnt vmcnt(12)" ::: "memory");
        __builtin_amdgcn_sched_barrier(0);
        __builtin_amdgcn_s_barrier();
        __builtin_amdgcn_sched_barrier(0);
#pragma unroll
        for (int ns = 0; ns < 4; ++ns)
            bfrB[ns] = *(const short8*)(wb[ns] + (size_t)(kc + 1) * 512);
        asm volatile("" ::: "memory");
        {
            int s = kc + 3; if (s > NKC - 1) s = NKC - 1;
            stage((kc + 3) & 3, s);
        }
        {
            const bf16* at = atile[kc & 3];
#pragma unroll
            for (int ms = 0; ms < 4; ++ms)
                afr[ms] = *(const short8*)(at + aoff[ms]);
        }
#pragma unroll
        for (int ms = 0; ms < 4; ++ms)
#pragma unroll
            for (int ns = 0; ns < 4; ++ns)
                acc[ms][ns] = __builtin_amdgcn_mfma_f32_16x16x32_bf16(
                    afr[ms], bfrA[ns], acc[ms][ns], 0, 0, 0);

        // ---- chunk kc+1: buffer (kc+1)&3, frags bfrB ----
        asm volatile("s_waitcnt vmcnt(12)" ::: "memory");
        __builtin_amdgcn_sched_barrier(0);
        __builtin_amdgcn_s_barrier();
        __builtin_amdgcn_sched_barrier(0);
        {
            int nb = kc + 2; if (nb > NKC - 1) nb = NKC - 1;
#pragma unroll
            for (int ns = 0; ns < 4; ++ns)
                bfrA[ns] = *(const short8*)(wb[ns] + (size_t)nb * 512);
        }
        asm volatile("" ::: "memory");
        {
            int s = kc + 4; if (s > NKC - 1) s = NKC - 1;
            stage((kc + 4) & 3, s);
        }
        {
            const bf16* at = atile[(kc + 1) & 3];
#pragma unroll
            for (int ms = 0; ms < 4; ++ms)
                afr[ms] = *(const short8*)(at + aoff[ms]);
        }
#pragma unroll
        for (int ms = 0; ms < 4; ++ms)
#pragma unroll
            for (int ns = 0; ns < 4; ++ns)
                acc[ms][ns] = __builtin_amdgcn_mfma_f32_16x16x32_bf16(
                    afr[ms], bfrB[ns], acc[ms][ns], 0, 0, 0);
    }

    // epilogue: D rows = px (quad*4+rg), cols = co (l15)
    float scl[4], bia[4];
#pragma unroll
    for (int ns = 0; ns < 4; ++ns) {
        int co = (nh * 8 + ni * 4 + ns) * 16 + l15;
        if (co >= 192) { scl[ns] = ep_scale[co - 192]; bia[ns] = ep_bias[co - 192]; }
    }
#pragma unroll
    for (int ms = 0; ms < 4; ++ms) {
#pragma unroll
        for (int rg = 0; rg < 4; ++rg) {
            int p = mt * 128 + mi * 64 + ms * 16 + quad * 4 + rg;
            if (p > 360) continue;
            size_t ppad = (size_t)b * PP + (p / WW + 1) * 21 + (p % WW + 1);
#pragma unroll
            for (int ns = 0; ns < 4; ++ns) {
                int co = (nh * 8 + ni * 4 + ns) * 16 + l15;
                float v = acc[ms][ns][rg];
                if (co < 192) {
                    reg_out[ppad * REG_C + co] = f2b(v);
                } else {
                    v = mish_f(v * scl[ns] + bia[ns]);
                    gp_out[((size_t)b * HW + p) * GPOOL_C + (co - 192)] = f2b(v);
                }
            }
        }
    }
}

// ------------------- conv2 (W x act -> channel-first fp32) ------------------
// Same pipeline. Block: 4 waves (pw 0..1 px-half x cw 0..1), tile 128co x 128px
// (blockIdx.z picks co half). A = fragmented weights, B = act frags. +resid.
__global__ __launch_bounds__(256, 3)
void conv2_kernel(const bf16* __restrict__ act,     // reg_pad [b][441][192]
                  const bf16* __restrict__ wfrag,   // [16][54][64][8]
                  const float* __restrict__ resid,
                  float* __restrict__ out) {
    const int CIN = 192, NKC = 54;
    __shared__ __align__(16) bf16 atile[4][128 * 32];
    const int b   = blockIdx.x;
    const int mt  = blockIdx.y;
    const int nh  = blockIdx.z;
    const int t   = threadIdx.x;
    const int w   = t >> 6, lane = t & 63;
    const int pw  = w >> 1, cw = w & 1;
    const int l15 = lane & 15, quad = lane >> 4;

    int row0 = t >> 2;
    int sq   = t & 3;
    int ss   = sq ^ ((row0 >> 1) & 3);
    int sp0  = mt * 128 + row0;      if (sp0 > 360) sp0 = 360;
    int sp1  = mt * 128 + row0 + 64; if (sp1 > 360) sp1 = 360;
    const bf16* sb0 = act + ((size_t)b * PP + (sp0 / WW) * 21 + (sp0 % WW)) * CIN + (ss << 3);
    const bf16* sb1 = act + ((size_t)b * PP + (sp1 / WW) * 21 + (sp1 % WW)) * CIN + (ss << 3);

    const bf16* wb[4];
#pragma unroll
    for (int ms = 0; ms < 4; ++ms)
        wb[ms] = wfrag + ((size_t)(nh * 8 + cw * 4 + ms) * NKC * 64 + lane) * 8;

    int aoff[4];
#pragma unroll
    for (int ns = 0; ns < 4; ++ns) {
        int row = pw * 64 + ns * 16 + l15;
        aoff[ns] = row * 32 + ((quad ^ ((row >> 1) & 3)) << 3);
    }

    auto stage = [&](int buf, int kc) {
        int r = kc / 6, c = kc % 6;
        int off = ((r / 3) * 21 + (r % 3)) * CIN + (c << 5);
        bf16* dst = &atile[buf][w << 9];
        gload_lds16(sb0 + off, dst);
        gload_lds16(sb1 + off, dst + 2048);
    };

    floatx4 acc[4][4];
#pragma unroll
    for (int i = 0; i < 4; ++i)
#pragma unroll
        for (int j = 0; j < 4; ++j) acc[i][j] = (floatx4){0.f, 0.f, 0.f, 0.f};

    short8 bfa[4], wfrA[4], wfrB[4];
    stage(0, 0);
    stage(1, 1);
    asm volatile("" ::: "memory");
#pragma unroll
    for (int ms = 0; ms < 4; ++ms) wfrA[ms] = *(const short8*)(wb[ms]);
    asm volatile("" ::: "memory");
    stage(2, 2);

    for (int kc = 0; kc < NKC; kc += 2) {
        // ---- chunk kc: buffer kc&3, frags wfrA ----
        if (kc == 0) asm volatile("s_waitcnt vmcnt(8)" ::: "memory");
        else         asm volatile("s_waitcnt vmcnt(12)" ::: "memory");
        __builtin_amdgcn_sched_barrier(0);
        __builtin_amdgcn_s_barrier();
        __builtin_amdgcn_sched_barrier(0);
#pragma unroll
        for (int ms = 0; ms < 4; ++ms)
            wfrB[ms] = *(const short8*)(wb[ms] + (size_t)(kc + 1) * 512);
        asm volatile("" ::: "memory");
        {
            int s = kc + 3; if (s > NKC - 1) s = NKC - 1;
            stage((kc + 3) & 3, s);
        }
        {
            const bf16* at = atile[kc & 3];
#pragma unroll
            for (int ns = 0; ns < 4; ++ns)
                bfa[ns] = *(const short8*)(at + aoff[ns]);
        }
#pragma unroll
        for (int ms = 0; ms < 4; ++ms)
#pragma unroll
            for (int ns = 0; ns < 4; ++ns)
                acc[ms][ns] = __builtin_amdgcn_mfma_f32_16x16x32_bf16(
                    wfrA[ms], bfa[ns], acc[ms][ns], 0, 0, 0);

        // ---- chunk kc+1: buffer (kc+1)&3, frags wfrB ----
        asm volatile("s_waitcnt vmcnt(12)" ::: "memory");
        __builtin_amdgcn_sched_barrier(0);
        __builtin_amdgcn_s_barrier();
        __builtin_amdgcn_sched_barrier(0);
        {
            int nb = kc + 2; if (nb > NKC - 1) nb = NKC - 1;
#pragma unroll
            for (int ms = 0; ms < 4; ++ms)
                wfrA[ms] = *(const short8*)(wb[ms] + (size_t)nb * 512);
        }
        asm volatile("" ::: "memory");
        {
            int s = kc + 4; if (s > NKC - 1) s = NKC - 1;
            stage((kc + 4) & 3, s);
        }
        {
            const bf16* at = atile[(kc + 1) & 3];
#pragma unroll
            for (int ns = 0; ns < 4; ++ns)
                bfa[ns] = *(const short8*)(at + aoff[ns]);
        }
#pragma unroll
        for (int ms = 0; ms < 4; ++ms)
#pragma unroll
            for (int ns = 0; ns < 4; ++ns)
                acc[ms][ns] = __builtin_amdgcn_mfma_f32_16x16x32_bf16(
                    wfrB[ms], bfa[ns], acc[ms][ns], 0, 0, 0);
    }

    // epilogue: D rows = co (quad*4+rg), cols = px (l15)
#pragma unroll
    for (int ns = 0; ns < 4; ++ns) {
        int p = mt * 128 + pw * 64 + ns * 16 + l15;
        if (p > 360) continue;
#pragma unroll
        for (int ms = 0; ms < 4; ++ms) {
#pragma unroll
            for (int rg = 0; rg < 4; ++rg) {
                int co = (nh * 8 + cw * 4 + ms) * 16 + quad * 4 + rg;
                size_t idx = ((size_t)b * TRUNK_C + co) * HW + p;
                out[idx] = acc[ms][ns][rg] + resid[idx];
            }
        }
    }
}

// --------------------- kata gpool + fused 192x192 linear --------------------
__global__ void gpool_lin_kernel(const bf16* __restrict__ gp, const float* __restrict__ w_lin,
                                 float* __restrict__ gpout) {
    __shared__ float ls[4][64], lm[4][64];
    __shared__ float pooled_s[192];
    int b = blockIdx.x;
    int t = threadIdx.x;          // 256
    int c = t & 63, sub = t >> 6;
    float s = 0.0f, mx = -1e30f;
    for (int p = sub; p < HW; p += 4) {
        float v = b2f(gp[((size_t)b * HW + p) * GPOOL_C + c]);
        s += v;
        mx = fmaxf(mx, v);
    }
    ls[sub][c] = s; lm[sub][c] = mx;
    __syncthreads();
    if (t < 64) {
        float ss = ls[0][t] + ls[1][t] + ls[2][t] + ls[3][t];
        float mm = fmaxf(fmaxf(lm[0][t], lm[1][t]), fmaxf(lm[2][t], lm[3][t]));
        float mean = ss * (1.0f / 361.0f);
        pooled_s[t] = mean;
        pooled_s[64 + t] = mean * 0.5f;     // (sqrt(361)-14)/10
        pooled_s[128 + t] = mm;
    }
    __syncthreads();
    if (t < 192) {
        const float4* wr4 = (const float4*)(w_lin + t * 192);
        float acc = 0.0f;
#pragma unroll 8
        for (int j = 0; j < 48; ++j) {
            float4 wv = wr4[j];
            acc = fmaf(pooled_s[j * 4 + 0], wv.x, acc);
            acc = fmaf(pooled_s[j * 4 + 1], wv.y, acc);
            acc = fmaf(pooled_s[j * 4 + 2], wv.z, acc);
            acc = fmaf(pooled_s[j * 4 + 3], wv.w, acc);
        }
        gpout[b * 192 + t] = acc;
    }
}

// ------------- add gpool bias + bn2 + mish, in-place on reg_pad -------------
// short8-vectorized: one thread per 8 channels (24 groups/pixel).
__global__ __launch_bounds__(256)
void add_bn2_mish_kernel(bf16* __restrict__ reg_pad, const float* __restrict__ gpout,
                         const float* __restrict__ bnbuf) {
    const int total = BATCH * HW * 24;
    int i = blockIdx.x * blockDim.x + threadIdx.x;
    if (i >= total) return;
    int g  = i % 24;
    int bp = i / 24;
    int p  = bp % HW;
    int b  = bp / HW;
    int pp = (p / WW + 1) * 21 + (p % WW + 1);
    size_t idx = ((size_t)b * PP + pp) * REG_C + g * 8;
    short8 v = *(const short8*)(reg_pad + idx);
    const float* gpo = gpout + b * 192 + g * 8;
    const float* sc  = bnbuf + 640 + g * 8;
    const float* bi  = bnbuf + 832 + g * 8;
    short8 o;
#pragma unroll
    for (int j = 0; j < 8; ++j) {
        short sj = v[j];
        bf16 h;
        __builtin_memcpy(&h, &sj, 2);
        float f = b2f(h) + gpo[j];
        f = f * sc[j] + bi[j];
        h = f2b(mish_f(f));
        __builtin_memcpy(&sj, &h, 2);
        o[j] = sj;
    }
    *(short8*)(reg_pad + idx) = o;
}

// ---------------------------------------------------------------------------
extern "C" void kernel_launch(void* const* d_in, const int* in_sizes, int n_in,
                              void* d_out, int out_size, void* d_ws, size_t ws_size,
                              hipStream_t stream) {
    const float* x     = (const float*)d_in[0];
    const float* bn1_g = (const float*)d_in[1];
    const float* bn1_b = (const float*)d_in[2];
    const float* bn1_m = (const float*)d_in[3];
    const float* bn1_v = (const float*)d_in[4];
    const float* w1a   = (const float*)d_in[5];
    const float* w1b   = (const float*)d_in[6];
    const float* bn1b_g = (const float*)d_in[7];
    const float* bn1b_b = (const float*)d_in[8];
    const float* bn1b_m = (const float*)d_in[9];
    const float* bn1b_v = (const float*)d_in[10];
    const float* w_lin  = (const float*)d_in[11];
    const float* bn2_g  = (const float*)d_in[12];
    const float* bn2_b  = (const float*)d_in[13];
    const float* bn2_m  = (const float*)d_in[14];
    const float* bn2_v  = (const float*)d_in[15];
    const float* w2     = (const float*)d_in[16];
    float* out = (float*)d_out;

    char* ws = (char*)d_ws;
    size_t off = 0;
    auto alloc = [&](size_t bytes) {
        void* p = ws + off;
        off += (bytes + 255) & ~(size_t)255;
        return p;
    };
    bf16*  act_pad = (bf16*)alloc((size_t)BATCH * PP * TRUNK_C * sizeof(bf16));
    bf16*  reg_pad = (bf16*)alloc((size_t)BATCH * PP * REG_C * sizeof(bf16));
    bf16*  gp      = (bf16*)alloc((size_t)BATCH * HW * GPOOL_C * sizeof(bf16));
    bf16*  w1c_p   = (bf16*)alloc((size_t)16 * 72 * 64 * 8 * sizeof(bf16));
    bf16*  w2_p    = (bf16*)alloc((size_t)16 * 54 * 64 * 8 * sizeof(bf16));
    float* gpout   = (float*)alloc((size_t)BATCH * 192 * sizeof(float));
    float* bnbuf   = (float*)alloc(1024 * sizeof(float));
    (void)ws_size;

    // 1. fused prep: weight frags + border zero + BN fold  (2179584 items)
    {
        const int total = (16 * 72 * 64 * 8) + (16 * 54 * 64 * 8)
                        + BATCH * 80 * 32 + BATCH * 80 * 24 + 512;
        hipLaunchKernelGGL(prep_kernel, dim3((total + 255) / 256), dim3(256), 0, stream,
                           bn1_g, bn1_b, bn1_m, bn1_v,
                           bn1b_g, bn1b_b, bn1b_m, bn1b_v,
                           bn2_g, bn2_b, bn2_m, bn2_v,
                           w1a, w1b, w2, w1c_p, w2_p, act_pad, reg_pad, bnbuf);
    }

    // 2. act_pad = mish(bn1(x)), LDS-tiled transpose to channel-last padded
    hipLaunchKernelGGL(bn1_mish_t_kernel, dim3(12, BATCH), dim3(256), 0, stream,
                       x, bnbuf, act_pad);

    // 3. fused conv1: reg_pad raw interior + gp = mish(bn1b(conv))
    hipLaunchKernelGGL(conv1_kernel, dim3(BATCH, 3, 2), dim3(256), 0, stream,
                       act_pad, w1c_p, reg_pad, gp, bnbuf + 512, bnbuf + 576);

    // 4. pooled = kata_gpool(gp); gpout = pooled @ w_lin^T (fused)
    hipLaunchKernelGGL(gpool_lin_kernel, dim3(BATCH), dim3(256), 0, stream,
                       gp, w_lin, gpout);

    // 5. reg_pad = mish(bn2(reg_pad + gpout)) in-place (interior only)
    {
        int total = BATCH * HW * 24;
        hipLaunchKernelGGL(add_bn2_mish_kernel, dim3((total + 255) / 256), dim3(256), 0, stream,
                           reg_pad, gpout, bnbuf);
    }

    // 6. out = conv(reg_pad, w2) + x, channel-first fp32
    hipLaunchKernelGGL(conv2_kernel, dim3(BATCH, 3, 2), dim3(256), 0, stream,
                       reg_pad, w2_p, x, out);
}

// Round 3
// 563.795 us; speedup vs baseline: 1.3284x; 1.1869x over previous
//
#include <hip/hip_runtime.h>
#include <hip/hip_bf16.h>
#include <math.h>

// ---------------------------------------------------------------------------
// GPoolBlock, round 10: BK=64 barrier intervals + XCD pair-swizzle + fusion.
//  - convs: 2 K-chunks per barrier interval (32 MFMA/barrier, was 16).
//    4-buffer rotation; interval v reads bufs (2v)&3,(2v+1)&3, stages
//    2v+2,2v+3 into the others -> mid-interval barrier deleted (no WAR).
//    Issue order per interval (fence-pinned): stage x4, bfrag(kc+1) x4,
//    [half1 ds_read+MFMA], bfrag(kc+2) x4, [half2] -> uniform vmcnt(8)
//    retires exactly stage(kc+2..3); vmcnt(4) for interval 0. setprio(1)
//    around MFMA clusters.
//  - flat 1536-block grid decoded so same-(b,mt) co-halves differ by 8 in
//    block id -> same XCD, co-dispatched -> shared A-tile hits L2
//    (round-9 FETCH tripled from the split being 768 ids apart).
//  - gpool_lin + add_bn2 fused (gpout stays in LDS; bn2 folded).
// Layouts: act channel-last zero-padded [b][441][C]; wfrag [cog][kc][lane][8].
// ---------------------------------------------------------------------------

#define BATCH   256
#define TRUNK_C 256
#define REG_C   192
#define GPOOL_C 64
#define HH      19
#define WW      19
#define HW      361
#define PP      441          // 21*21 padded pixels
#define EPS     1e-5f

typedef __hip_bfloat16 bf16;
typedef __attribute__((ext_vector_type(8))) short short8;
typedef __attribute__((ext_vector_type(4))) float floatx4;

__device__ __forceinline__ float b2f(bf16 v) { return __bfloat162float(v); }
__device__ __forceinline__ bf16  f2b(float v) { return __float2bfloat16(v); }

// mish(x) = x*tanh(softplus(x)); with u=e^x: tanh(log(1+u)) = u(u+2)/(u(u+2)+2)
__device__ __forceinline__ float mish_f(float v) {
    if (v > 20.0f) return v;           // tanh(softplus(20)) == 1 to fp32
    float u = __expf(v);
    float n = u * (u + 2.0f);
    return v * __fdividef(n, n + 2.0f);
}

__device__ __forceinline__ void gload_lds16(const void* gsrc, void* lds) {
    __builtin_amdgcn_global_load_lds(
        (const __attribute__((address_space(1))) void*)gsrc,
        (__attribute__((address_space(3))) void*)lds, 16, 0, 0);
}

// ---------------- fused prep: BN fold + weight frags + border zero ----------
// bnbuf: [0:256] bn1_s [256:512] bn1_b [512:576] bn1b_s [576:640] bn1b_b
//        [640:832] bn2_s [832:1024] bn2_b
__global__ void prep_kernel(
    const float* g1, const float* b1, const float* m1, const float* v1,
    const float* g1b, const float* b1b, const float* m1b, const float* v1b,
    const float* g2, const float* b2, const float* m2, const float* v2,
    const float* __restrict__ w1a, const float* __restrict__ w1b,
    const float* __restrict__ w2,
    bf16* __restrict__ w1c_p, bf16* __restrict__ w2_p,
    bf16* __restrict__ act_pad, bf16* __restrict__ reg_pad,
    float* bnbuf)
{
    const int T1  = 16 * 72 * 64 * 8;     // 589824
    const int T2  = 16 * 54 * 64 * 8;     // 442368
    const int TW  = T1 + T2;              // 1032192
    const int TBa = BATCH * 80 * 32;      // act border short8 groups 655360
    const int TBr = BATCH * 80 * 24;      // reg border short8 groups 491520
    int i = blockIdx.x * blockDim.x + threadIdx.x;
    if (i < TW) {
        if (i < T1) {
            int j = i & 7, lane = (i >> 3) & 63;
            int kc = (i >> 9) % 72, cog = (i >> 9) / 72;
            int co = cog * 16 + (lane & 15);
            int k = kc * 32 + ((lane >> 4) << 3) + j;
            int r = k >> 8, ci = k & 255;
            float v = (co < 192) ? w1a[co * 2304 + ci * 9 + r]
                                 : w1b[(co - 192) * 2304 + ci * 9 + r];
            w1c_p[i] = f2b(v);
        } else {
            int i2 = i - T1;
            int j = i2 & 7, lane = (i2 >> 3) & 63;
            int kc = (i2 >> 9) % 54, cog = (i2 >> 9) / 54;
            int co = cog * 16 + (lane & 15);
            int k = kc * 32 + ((lane >> 4) << 3) + j;
            int r = k / 192, ci = k % 192;
            w2_p[i2] = f2b(w2[co * 1728 + ci * 9 + r]);
        }
    } else if (i < TW + TBa + TBr) {
        int j = i - TW;
        bool isact = j < TBa;
        if (!isact) j -= TBa;
        int nb = isact ? 32 : 24;
        int b = j / (80 * nb);
        int rem = j - b * (80 * nb);
        int e = rem / nb, g = rem - (rem / nb) * nb;
        int pp;
        if (e < 21) pp = e;                        // row 0
        else if (e < 42) pp = 420 + (e - 21);      // row 20
        else if (e < 61) pp = (e - 41) * 21;       // col 0, rows 1..19
        else pp = (e - 60) * 21 + 20;              // col 20, rows 1..19
        short8 z = {0, 0, 0, 0, 0, 0, 0, 0};
        if (isact) *(short8*)(act_pad + ((size_t)b * PP + pp) * TRUNK_C + g * 8) = z;
        else       *(short8*)(reg_pad + ((size_t)b * PP + pp) * REG_C + g * 8) = z;
    } else {
        int t = i - (TW + TBa + TBr);
        if (t < 256) {
            float s = g1[t] / sqrtf(v1[t] + EPS);
            bnbuf[t] = s;
            bnbuf[256 + t] = b1[t] - m1[t] * s;
        } else if (t < 320) {
            int c = t - 256;
            float s = g1b[c] / sqrtf(v1b[c] + EPS);
            bnbuf[512 + c] = s;
            bnbuf[576 + c] = b1b[c] - m1b[c] * s;
        } else if (t < 512) {
            int c = t - 320;
            float s = g2[c] / sqrtf(v2[c] + EPS);
            bnbuf[640 + c] = s;
            bnbuf[832 + c] = b2[c] - m2[c] * s;
        }
    }
}

// ------- bn1+mish + LDS transpose: x [b][256][361] fp32 -> act_pad CL bf16 --
__global__ __launch_bounds__(256)
void bn1_mish_t_kernel(const float* __restrict__ x, const float* __restrict__ bnbuf,
                       bf16* __restrict__ act_pad) {
    __shared__ float lds[256][32];    // XOR-swizzled columns
    int pc = blockIdx.x;              // pixel chunk of 32 (12 chunks)
    int b  = blockIdx.y;
    int t  = threadIdx.x;
    int p0 = pc * 32;
    int px = t & 31;
#pragma unroll
    for (int it = 0; it < 32; ++it) {          // 32 passes x 8 channels = 256
        int ci = it * 8 + (t >> 5);
        int p  = p0 + px;
        float v = 0.0f;
        if (p < HW) v = x[((size_t)b * TRUNK_C + ci) * HW + p];
        v = v * bnbuf[ci] + bnbuf[256 + ci];
        lds[ci][px ^ (ci >> 3)] = mish_f(v);
    }
    __syncthreads();
#pragma unroll
    for (int it = 0; it < 4; ++it) {
        int pl = it * 8 + (t >> 5);
        int p  = p0 + pl;
        if (p >= HW) continue;
        int ch = t & 31;                       // channel block: ch*8 .. ch*8+7
        short8 vv;
#pragma unroll
        for (int j = 0; j < 8; ++j) {
            bf16 h = f2b(lds[ch * 8 + j][pl ^ ch]);
            short s;
            __builtin_memcpy(&s, &h, 2);
            vv[j] = s;
        }
        int pp = (p / WW + 1) * 21 + (p % WW + 1);
        *(short8*)(act_pad + ((size_t)b * PP + pp) * TRUNK_C + ch * 8) = vv;
    }
}

// ------------------ grid decode: co-halves 8 ids apart ----------------------
// wg in [0,1536): g=wg>>4 (96 groups), r=wg&15; nh=r>>3; pair=(g<<3)|(r&7);
// b = pair/3, mt = pair%3. Same (b,mt) pair -> ids differ by 8 -> same XCD.
__device__ __forceinline__ void decode_wg(int wg, int& b, int& mt, int& nh) {
    int g = wg >> 4, r = wg & 15;
    nh = r >> 3;
    int pr = (g << 3) | (r & 7);
    b = pr / 3;
    mt = pr - b * 3;
}

// ---------------------- conv1 fused (act x W -> 256 co) ---------------------
// Block: 256 thr (4 waves: mi 0..1 x ni 0..1). Tile M=128 px, N=128 co.
// BK=64 barrier interval: 2 chunks per {vmcnt(8); s_barrier}. 4 LDS buffers;
// interval v reads bufs (2v)&3,(2v+1)&3, stages chunks 2v+2,2v+3.
// co<192 -> reg_pad raw (padded CL); co>=192 -> gp (bn1b+mish, CL).
__global__ __launch_bounds__(256, 3)
void conv1_kernel(const bf16* __restrict__ act,     // [b][441][256]
                  const bf16* __restrict__ wfrag,   // [16][72][64][8]
                  bf16* __restrict__ reg_out,       // [b][441][192]
                  bf16* __restrict__ gp_out,        // [b][361][64]
                  const float* __restrict__ ep_scale, const float* __restrict__ ep_bias) {
    const int CIN = 256, NKC = 72;
    __shared__ __align__(16) bf16 atile[4][128 * 32];
    int b, mt, nh;
    decode_wg(blockIdx.x, b, mt, nh);
    const int t   = threadIdx.x;
    const int w   = t >> 6, lane = t & 63;
    const int mi  = w >> 1, ni = w & 1;
    const int l15 = lane & 15, quad = lane >> 4;

    // staging: thread t covers LDS rows (t>>2) and (t>>2)+64, 16B sub-chunk
    int row0 = t >> 2;
    int sq   = t & 3;
    int ss   = sq ^ ((row0 >> 1) & 3);       // swizzled ci sub-chunk
    int sp0  = mt * 128 + row0;      if (sp0 > 360) sp0 = 360;
    int sp1  = mt * 128 + row0 + 64; if (sp1 > 360) sp1 = 360;
    const bf16* sb0 = act + ((size_t)b * PP + (sp0 / WW) * 21 + (sp0 % WW)) * CIN + (ss << 3);
    const bf16* sb1 = act + ((size_t)b * PP + (sp1 / WW) * 21 + (sp1 % WW)) * CIN + (ss << 3);

    // B-frag bases: cog = nh*8 + ni*4 + ns
    const bf16* wb[4];
#pragma unroll
    for (int ns = 0; ns < 4; ++ns)
        wb[ns] = wfrag + ((size_t)(nh * 8 + ni * 4 + ns) * NKC * 64 + lane) * 8;

    int aoff[4];
#pragma unroll
    for (int ms = 0; ms < 4; ++ms) {
        int row = mi * 64 + ms * 16 + l15;
        aoff[ms] = row * 32 + ((quad ^ ((row >> 1) & 3)) << 3);
    }

    auto stage = [&](int buf, int kc) {
        int r = kc >> 3, c = kc & 7;
        int off = ((r / 3) * 21 + (r % 3)) * CIN + (c << 5);
        bf16* dst = &atile[buf][w << 9];
        gload_lds16(sb0 + off, dst);
        gload_lds16(sb1 + off, dst + 2048);
    };

    floatx4 acc[4][4];
#pragma unroll
    for (int i = 0; i < 4; ++i)
#pragma unroll
        for (int j = 0; j < 4; ++j) acc[i][j] = (floatx4){0.f, 0.f, 0.f, 0.f};

    short8 afr[4], bfrA[4], bfrB[4];
    // prologue: stage(0), stage(1) [4 ops], fence, bfrA(0) [4 ops]
    stage(0, 0);
    stage(1, 1);
    asm volatile("" ::: "memory");
#pragma unroll
    for (int ns = 0; ns < 4; ++ns) bfrA[ns] = *(const short8*)(wb[ns]);

    for (int kc = 0; kc < NKC; kc += 2) {
        if (kc == 0) asm volatile("s_waitcnt vmcnt(4)" ::: "memory");
        else         asm volatile("s_waitcnt vmcnt(8)" ::: "memory");
        __builtin_amdgcn_sched_barrier(0);
        __builtin_amdgcn_s_barrier();
        __builtin_amdgcn_sched_barrier(0);
        // stage the next interval's two chunks (bufs disjoint from read bufs)
        {
            int s0 = kc + 2; if (s0 > NKC - 1) s0 = NKC - 1;
            int s1 = kc + 3; if (s1 > NKC - 1) s1 = NKC - 1;
            stage((kc + 2) & 3, s0);
            stage((kc + 3) & 3, s1);
        }
        asm volatile("" ::: "memory");
#pragma unroll
        for (int ns = 0; ns < 4; ++ns)
            bfrB[ns] = *(const short8*)(wb[ns] + (size_t)(kc + 1) * 512);
        asm volatile("" ::: "memory");
        // ---- half 1: chunk kc, buffer kc&3, frags bfrA ----
        {
            const bf16* at = atile[kc & 3];
#pragma unroll
            for (int ms = 0; ms < 4; ++ms)
                afr[ms] = *(const short8*)(at + aoff[ms]);
        }
        __builtin_amdgcn_s_setprio(1);
#pragma unroll
        for (int ms = 0; ms < 4; ++ms)
#pragma unroll
            for (int ns = 0; ns < 4; ++ns)
                acc[ms][ns] = __builtin_amdgcn_mfma_f32_16x16x32_bf16(
                    afr[ms], bfrA[ns], acc[ms][ns], 0, 0, 0);
        __builtin_amdgcn_s_setprio(0);
        // bfrA for next interval's first chunk
        {
            int nb = kc + 2; if (nb > NKC - 1) nb = NKC - 1;
#pragma unroll
            for (int ns = 0; ns < 4; ++ns)
                bfrA[ns] = *(const short8*)(wb[ns] + (size_t)nb * 512);
        }
        asm volatile("" ::: "memory");
        // ---- half 2: chunk kc+1, buffer (kc+1)&3, frags bfrB ----
        {
            const bf16* at = atile[(kc + 1) & 3];
#pragma unroll
            for (int ms = 0; ms < 4; ++ms)
                afr[ms] = *(const short8*)(at + aoff[ms]);
        }
        __builtin_amdgcn_s_setprio(1);
#pragma unroll
        for (int ms = 0; ms < 4; ++ms)
#pragma unroll
            for (int ns = 0; ns < 4; ++ns)
                acc[ms][ns] = __builtin_amdgcn_mfma_f32_16x16x32_bf16(
                    afr[ms], bfrB[ns], acc[ms][ns], 0, 0, 0);
        __builtin_amdgcn_s_setprio(0);
    }

    // epilogue: D rows = px (quad*4+rg), cols = co (l15)
    float scl[4], bia[4];
#pragma unroll
    for (int ns = 0; ns < 4; ++ns) {
        int co = (nh * 8 + ni * 4 + ns) * 16 + l15;
        if (co >= 192) { scl[ns] = ep_scale[co - 192]; bia[ns] = ep_bias[co - 192]; }
    }
#pragma unroll
    for (int ms = 0; ms < 4; ++ms) {
#pragma unroll
        for (int rg = 0; rg < 4; ++rg) {
            int p = mt * 128 + mi * 64 + ms * 16 + quad * 4 + rg;
            if (p > 360) continue;
            size_t ppad = (size_t)b * PP + (p / WW + 1) * 21 + (p % WW + 1);
#pragma unroll
            for (int ns = 0; ns < 4; ++ns) {
                int co = (nh * 8 + ni * 4 + ns) * 16 + l15;
                float v = acc[ms][ns][rg];
                if (co < 192) {
                    reg_out[ppad * REG_C + co] = f2b(v);
                } else {
                    v = mish_f(v * scl[ns] + bia[ns]);
                    gp_out[((size_t)b * HW + p) * GPOOL_C + (co - 192)] = f2b(v);
                }
            }
        }
    }
}

// ------------------- conv2 (W x act -> channel-first fp32) ------------------
// Same BK=64 interval pipeline. A = fragmented weights, B = act frags. +resid.
__global__ __launch_bounds__(256, 3)
void conv2_kernel(const bf16* __restrict__ act,     // reg_pad [b][441][192]
                  const bf16* __restrict__ wfrag,   // [16][54][64][8]
                  const float* __restrict__ resid,
                  float* __restrict__ out) {
    const int CIN = 192, NKC = 54;
    __shared__ __align__(16) bf16 atile[4][128 * 32];
    int b, mt, nh;
    decode_wg(blockIdx.x, b, mt, nh);
    const int t   = threadIdx.x;
    const int w   = t >> 6, lane = t & 63;
    const int pw  = w >> 1, cw = w & 1;
    const int l15 = lane & 15, quad = lane >> 4;

    int row0 = t >> 2;
    int sq   = t & 3;
    int ss   = sq ^ ((row0 >> 1) & 3);
    int sp0  = mt * 128 + row0;      if (sp0 > 360) sp0 = 360;
    int sp1  = mt * 128 + row0 + 64; if (sp1 > 360) sp1 = 360;
    const bf16* sb0 = act + ((size_t)b * PP + (sp0 / WW) * 21 + (sp0 % WW)) * CIN + (ss << 3);
    const bf16* sb1 = act + ((size_t)b * PP + (sp1 / WW) * 21 + (sp1 % WW)) * CIN + (ss << 3);

    const bf16* wb[4];
#pragma unroll
    for (int ms = 0; ms < 4; ++ms)
        wb[ms] = wfrag + ((size_t)(nh * 8 + cw * 4 + ms) * NKC * 64 + lane) * 8;

    int aoff[4];
#pragma unroll
    for (int ns = 0; ns < 4; ++ns) {
        int row = pw * 64 + ns * 16 + l15;
        aoff[ns] = row * 32 + ((quad ^ ((row >> 1) & 3)) << 3);
    }

    auto stage = [&](int buf, int kc) {
        int r = kc / 6, c = kc % 6;
        int off = ((r / 3) * 21 + (r % 3)) * CIN + (c << 5);
        bf16* dst = &atile[buf][w << 9];
        gload_lds16(sb0 + off, dst);
        gload_lds16(sb1 + off, dst + 2048);
    };

    floatx4 acc[4][4];
#pragma unroll
    for (int i = 0; i < 4; ++i)
#pragma unroll
        for (int j = 0; j < 4; ++j) acc[i][j] = (floatx4){0.f, 0.f, 0.f, 0.f};

    short8 bfa[4], wfrA[4], wfrB[4];
    stage(0, 0);
    stage(1, 1);
    asm volatile("" ::: "memory");
#pragma unroll
    for (int ms = 0; ms < 4; ++ms) wfrA[ms] = *(const short8*)(wb[ms]);

    for (int kc = 0; kc < NKC; kc += 2) {
        if (kc == 0) asm volatile("s_waitcnt vmcnt(4)" ::: "memory");
        else         asm volatile("s_waitcnt vmcnt(8)" ::: "memory");
        __builtin_amdgcn_sched_barrier(0);
        __builtin_amdgcn_s_barrier();
        __builtin_amdgcn_sched_barrier(0);
        {
            int s0 = kc + 2; if (s0 > NKC - 1) s0 = NKC - 1;
            int s1 = kc + 3; if (s1 > NKC - 1) s1 = NKC - 1;
            stage((kc + 2) & 3, s0);
            stage((kc + 3) & 3, s1);
        }
        asm volatile("" ::: "memory");
#pragma unroll
        for (int ms = 0; ms < 4; ++ms)
            wfrB[ms] = *(const short8*)(wb[ms] + (size_t)(kc + 1) * 512);
        asm volatile("" ::: "memory");
        // ---- half 1: chunk kc ----
        {
            const bf16* at = atile[kc & 3];
#pragma unroll
            for (int ns = 0; ns < 4; ++ns)
                bfa[ns] = *(const short8*)(at + aoff[ns]);
        }
        __builtin_amdgcn_s_setprio(1);
#pragma unroll
        for (int ms = 0; ms < 4; ++ms)
#pragma unroll
            for (int ns = 0; ns < 4; ++ns)
                acc[ms][ns] = __builtin_amdgcn_mfma_f32_16x16x32_bf16(
                    wfrA[ms], bfa[ns], acc[ms][ns], 0, 0, 0);
        __builtin_amdgcn_s_setprio(0);
        {
            int nb = kc + 2; if (nb > NKC - 1) nb = NKC - 1;
#pragma unroll
            for (int ms = 0; ms < 4; ++ms)
                wfrA[ms] = *(const short8*)(wb[ms] + (size_t)nb * 512);
        }
        asm volatile("" ::: "memory");
        // ---- half 2: chunk kc+1 ----
        {
            const bf16* at = atile[(kc + 1) & 3];
#pragma unroll
            for (int ns = 0; ns < 4; ++ns)
                bfa[ns] = *(const short8*)(at + aoff[ns]);
        }
        __builtin_amdgcn_s_setprio(1);
#pragma unroll
        for (int ms = 0; ms < 4; ++ms)
#pragma unroll
            for (int ns = 0; ns < 4; ++ns)
                acc[ms][ns] = __builtin_amdgcn_mfma_f32_16x16x32_bf16(
                    wfrB[ms], bfa[ns], acc[ms][ns], 0, 0, 0);
        __builtin_amdgcn_s_setprio(0);
    }

    // epilogue: D rows = co (quad*4+rg), cols = px (l15)
#pragma unroll
    for (int ns = 0; ns < 4; ++ns) {
        int p = mt * 128 + pw * 64 + ns * 16 + l15;
        if (p > 360) continue;
#pragma unroll
        for (int ms = 0; ms < 4; ++ms) {
#pragma unroll
            for (int rg = 0; rg < 4; ++rg) {
                int co = (nh * 8 + cw * 4 + ms) * 16 + quad * 4 + rg;
                size_t idx = ((size_t)b * TRUNK_C + co) * HW + p;
                out[idx] = acc[ms][ns][rg] + resid[idx];
            }
        }
    }
}

// ------- fused: kata gpool + 192x192 linear + add + bn2 + mish (in-place) ---
// One block per batch. gpout never leaves LDS; bn2 folded into the per-pixel
// pass: (reg+go)*s2+b2 = reg*s2 + (go*s2+b2).
__global__ __launch_bounds__(256)
void gpool_bn2_kernel(const bf16* __restrict__ gp, const float* __restrict__ w_lin,
                      const float* __restrict__ bnbuf, bf16* __restrict__ reg_pad) {
    __shared__ float ls[4][64], lm[4][64];
    __shared__ float pooled_s[192];
    __shared__ float gob_s[192];     // go*s2 + b2
    __shared__ float s2_s[192];      // bn2 scale
    int b = blockIdx.x;
    int t = threadIdx.x;          // 256
    int c = t & 63, sub = t >> 6;
    float s = 0.0f, mx = -1e30f;
    for (int p = sub; p < HW; p += 4) {
        float v = b2f(gp[((size_t)b * HW + p) * GPOOL_C + c]);
        s += v;
        mx = fmaxf(mx, v);
    }
    ls[sub][c] = s; lm[sub][c] = mx;
    __syncthreads();
    if (t < 64) {
        float ss = ls[0][t] + ls[1][t] + ls[2][t] + ls[3][t];
        float mm = fmaxf(fmaxf(lm[0][t], lm[1][t]), fmaxf(lm[2][t], lm[3][t]));
        float mean = ss * (1.0f / 361.0f);
        pooled_s[t] = mean;
        pooled_s[64 + t] = mean * 0.5f;     // (sqrt(361)-14)/10
        pooled_s[128 + t] = mm;
    }
    __syncthreads();
    if (t < 192) {
        const float4* wr4 = (const float4*)(w_lin + t * 192);
        float acc = 0.0f;
#pragma unroll 8
        for (int j = 0; j < 48; ++j) {
            float4 wv = wr4[j];
            acc = fmaf(pooled_s[j * 4 + 0], wv.x, acc);
            acc = fmaf(pooled_s[j * 4 + 1], wv.y, acc);
            acc = fmaf(pooled_s[j * 4 + 2], wv.z, acc);
            acc = fmaf(pooled_s[j * 4 + 3], wv.w, acc);
        }
        float s2 = bnbuf[640 + t];
        s2_s[t]  = s2;
        gob_s[t] = acc * s2 + bnbuf[832 + t];
    }
    __syncthreads();
    // per-pixel pass: 361 px x 24 short8 groups, in-place rmw on reg_pad
    for (int i = t; i < HW * 24; i += 256) {
        int p = i / 24, g = i - (i / 24) * 24;
        int pp = (p / WW + 1) * 21 + (p % WW + 1);
        size_t idx = ((size_t)b * PP + pp) * REG_C + g * 8;
        short8 v = *(const short8*)(reg_pad + idx);
        short8 o;
#pragma unroll
        for (int j = 0; j < 8; ++j) {
            int cc = g * 8 + j;
            short sj = v[j];
            bf16 h;
            __builtin_memcpy(&h, &sj, 2);
            float f = b2f(h) * s2_s[cc] + gob_s[cc];
            h = f2b(mish_f(f));
            __builtin_memcpy(&sj, &h, 2);
            o[j] = sj;
        }
        *(short8*)(reg_pad + idx) = o;
    }
}

// ---------------------------------------------------------------------------
extern "C" void kernel_launch(void* const* d_in, const int* in_sizes, int n_in,
                              void* d_out, int out_size, void* d_ws, size_t ws_size,
                              hipStream_t stream) {
    const float* x     = (const float*)d_in[0];
    const float* bn1_g = (const float*)d_in[1];
    const float* bn1_b = (const float*)d_in[2];
    const float* bn1_m = (const float*)d_in[3];
    const float* bn1_v = (const float*)d_in[4];
    const float* w1a   = (const float*)d_in[5];
    const float* w1b   = (const float*)d_in[6];
    const float* bn1b_g = (const float*)d_in[7];
    const float* bn1b_b = (const float*)d_in[8];
    const float* bn1b_m = (const float*)d_in[9];
    const float* bn1b_v = (const float*)d_in[10];
    const float* w_lin  = (const float*)d_in[11];
    const float* bn2_g  = (const float*)d_in[12];
    const float* bn2_b  = (const float*)d_in[13];
    const float* bn2_m  = (const float*)d_in[14];
    const float* bn2_v  = (const float*)d_in[15];
    const float* w2     = (const float*)d_in[16];
    float* out = (float*)d_out;

    char* ws = (char*)d_ws;
    size_t off = 0;
    auto alloc = [&](size_t bytes) {
        void* p = ws + off;
        off += (bytes + 255) & ~(size_t)255;
        return p;
    };
    bf16*  act_pad = (bf16*)alloc((size_t)BATCH * PP * TRUNK_C * sizeof(bf16));
    bf16*  reg_pad = (bf16*)alloc((size_t)BATCH * PP * REG_C * sizeof(bf16));
    bf16*  gp      = (bf16*)alloc((size_t)BATCH * HW * GPOOL_C * sizeof(bf16));
    bf16*  w1c_p   = (bf16*)alloc((size_t)16 * 72 * 64 * 8 * sizeof(bf16));
    bf16*  w2_p    = (bf16*)alloc((size_t)16 * 54 * 64 * 8 * sizeof(bf16));
    float* bnbuf   = (float*)alloc(1024 * sizeof(float));
    (void)ws_size;

    // 1. fused prep: weight frags + border zero + BN fold
    {
        const int total = (16 * 72 * 64 * 8) + (16 * 54 * 64 * 8)
                        + BATCH * 80 * 32 + BATCH * 80 * 24 + 512;
        hipLaunchKernelGGL(prep_kernel, dim3((total + 255) / 256), dim3(256), 0, stream,
                           bn1_g, bn1_b, bn1_m, bn1_v,
                           bn1b_g, bn1b_b, bn1b_m, bn1b_v,
                           bn2_g, bn2_b, bn2_m, bn2_v,
                           w1a, w1b, w2, w1c_p, w2_p, act_pad, reg_pad, bnbuf);
    }

    // 2. act_pad = mish(bn1(x)), LDS-tiled transpose to channel-last padded
    hipLaunchKernelGGL(bn1_mish_t_kernel, dim3(12, BATCH), dim3(256), 0, stream,
                       x, bnbuf, act_pad);

    // 3. fused conv1: reg_pad raw interior + gp = mish(bn1b(conv))
    hipLaunchKernelGGL(conv1_kernel, dim3(1536), dim3(256), 0, stream,
                       act_pad, w1c_p, reg_pad, gp, bnbuf + 512, bnbuf + 576);

    // 4. gpool + lin + add + bn2 + mish, in-place on reg_pad
    hipLaunchKernelGGL(gpool_bn2_kernel, dim3(BATCH), dim3(256), 0, stream,
                       gp, w_lin, bnbuf, reg_pad);

    // 5. out = conv(reg_pad, w2) + x, channel-first fp32
    hipLaunchKernelGGL(conv2_kernel, dim3(1536), dim3(256), 0, stream,
                       reg_pad, w2_p, x, out);
}